// Round 1
// baseline (966.880 us; speedup 1.0000x reference)
//
#include <hip/hip_runtime.h>

typedef __attribute__((ext_vector_type(8))) short short8;
typedef __attribute__((ext_vector_type(4))) float f32x4;

__device__ inline ushort f2bf(float f) {
  union { float f; unsigned u; } v; v.f = f;
  return (ushort)((v.u + 0x7fffu + ((v.u >> 16) & 1u)) >> 16);
}

// ---------------- weight prep: transpose + cast to bf16 ----------------
// Wt[n][k] = bf16(pi_w[k][n])   n<1024, k<256
// iiWt[n][k] = bf16(ii_w[k][n]) n<128,  k<128
__global__ __launch_bounds__(256)
void prep_weights(const float* __restrict__ pi_w, const float* __restrict__ ii_w,
                  ushort* __restrict__ Wt, ushort* __restrict__ iiWt)
{
  int tid = blockIdx.x * 256 + threadIdx.x;
  if (tid < 256 * 1024) {
    int n = tid >> 8, k = tid & 255;
    Wt[tid] = f2bf(pi_w[k * 1024 + n]);
  } else if (tid < 256 * 1024 + 128 * 128) {
    int t = tid - 256 * 1024;
    int n = t >> 7, k = t & 127;
    iiWt[t] = f2bf(ii_w[k * 128 + n]);
  }
}

// ---------------- pp: h = tanh(tanh(p1@W1+b1)@W2+b2) -> bf16 ----------------
__global__ __launch_bounds__(256)
void pp_kernel(const float* __restrict__ p1,
               const float* __restrict__ w1, const float* __restrict__ b1,
               const float* __restrict__ w2, const float* __restrict__ b2,
               ushort* __restrict__ hbf, int N)
{
  __shared__ float p1s[32 * 128];
  __shared__ float h1s[32 * 128];
  const int tid = threadIdx.x;
  const int n0 = blockIdx.x * 32;

  #pragma unroll
  for (int p = 0; p < 4; ++p) {
    int off = (p * 256 + tid) * 4;
    int n = n0 + (off >> 7);
    float4 v = make_float4(0.f, 0.f, 0.f, 0.f);
    if (n < N) v = *(const float4*)(p1 + (size_t)n0 * 128 + off);
    *(float4*)(p1s + off) = v;
  }
  __syncthreads();

  const int c = tid & 127;
  const int nset = tid >> 7;
  float acc[16];

  #pragma unroll
  for (int n = 0; n < 16; ++n) acc[n] = b1[c];
  for (int k = 0; k < 128; k += 4) {
    float wa = w1[(k + 0) * 128 + c];
    float wb = w1[(k + 1) * 128 + c];
    float wc = w1[(k + 2) * 128 + c];
    float wd = w1[(k + 3) * 128 + c];
    #pragma unroll
    for (int n = 0; n < 16; ++n) {
      const float4 pv = *(const float4*)(p1s + (nset * 16 + n) * 128 + k);
      acc[n] += pv.x * wa + pv.y * wb + pv.z * wc + pv.w * wd;
    }
  }
  #pragma unroll
  for (int n = 0; n < 16; ++n) h1s[(nset * 16 + n) * 128 + c] = tanhf(acc[n]);
  __syncthreads();

  #pragma unroll
  for (int n = 0; n < 16; ++n) acc[n] = b2[c];
  for (int k = 0; k < 128; k += 4) {
    float wa = w2[(k + 0) * 128 + c];
    float wb = w2[(k + 1) * 128 + c];
    float wc = w2[(k + 2) * 128 + c];
    float wd = w2[(k + 3) * 128 + c];
    #pragma unroll
    for (int n = 0; n < 16; ++n) {
      const float4 pv = *(const float4*)(h1s + (nset * 16 + n) * 128 + k);
      acc[n] += pv.x * wa + pv.y * wb + pv.z * wc + pv.w * wd;
    }
  }
  #pragma unroll
  for (int n = 0; n < 16; ++n) {
    int node = n0 + nset * 16 + n;
    if (node < N) hbf[(size_t)node * 128 + c] = f2bf(tanhf(acc[n]));
  }
}

// ---------------- fused edge kernel ----------------
// Per block: 64 edges. X = [h[idx_i]|h[idx_j]] (64x256 bf16, swizzled LDS).
// pi GEMM (MFMA 16x16x32 bf16, B streamed from global Wt) + basis fold -> Y(64x128 bf16)
// ii GEMM (MFMA) + tanh + atomic scatter-add to out[idx_j].
__global__ __launch_bounds__(256, 2)
void edge_kernel(const ushort* __restrict__ hbf,
                 const int* __restrict__ idx_i, const int* __restrict__ idx_j,
                 const float* __restrict__ basis,
                 const ushort* __restrict__ Wt,    // [1024][256] bf16
                 const float* __restrict__ pi_b,   // [1024]
                 const ushort* __restrict__ iiWt,  // [128][128] bf16
                 const float* __restrict__ ii_b,   // [128]
                 float* __restrict__ out, int E)
{
  __shared__ ushort Xs[64 * 256];   // rows of 512B, byte ^= (e&7)<<4
  __shared__ ushort Ys[64 * 128];   // rows of 256B, byte ^= (e&7)<<4
  __shared__ float  basis_s[64 * 8];
  __shared__ int    idxj_s[64];

  const int tid = threadIdx.x;
  const int wave = tid >> 6;
  const int lane = tid & 63;
  const int lane16 = lane & 15;
  const int lgrp = lane >> 4;
  const size_t e0 = (size_t)blockIdx.x * 64;

  // --- stage X (gather 128 rows of 256B) ---
  #pragma unroll
  for (int pass = 0; pass < 8; ++pass) {
    int r = pass * 16 + (tid >> 4);
    int l16 = tid & 15;
    int e = r >> 1;
    size_t eg = e0 + e; if (eg >= (size_t)E) eg = (size_t)E - 1;
    int node = (r & 1) ? idx_j[eg] : idx_i[eg];
    int4 v = *(const int4*)(hbf + (size_t)node * 128 + l16 * 8);
    int kb = ((r & 1) * 128 + l16 * 8) * 2;
    *(int4*)((char*)Xs + e * 512 + (kb ^ ((e & 7) << 4))) = v;
  }
  {
    size_t base = e0 * 8;
    size_t lim = (size_t)E * 8 - 1;
    size_t i1 = base + tid;        if (i1 > lim) i1 = lim;
    size_t i2 = base + 256 + tid;  if (i2 > lim) i2 = lim;
    basis_s[tid] = basis[i1];
    basis_s[tid + 256] = basis[i2];
    if (tid < 64) {
      size_t eg = e0 + tid; if (eg >= (size_t)E) eg = (size_t)E - 1;
      idxj_s[tid] = idx_j[eg];
    }
  }
  __syncthreads();

  // --- pi GEMM over 8 column tiles of 128 (=16 y-cols each) ---
  for (int ct = 0; ct < 8; ++ct) {
    f32x4 acc[4][2];
    #pragma unroll
    for (int mi = 0; mi < 4; ++mi)
      #pragma unroll
      for (int nf = 0; nf < 2; ++nf)
        acc[mi][nf] = (f32x4){0.f, 0.f, 0.f, 0.f};

    #pragma unroll
    for (int ks = 0; ks < 8; ++ks) {
      short8 a[4];
      #pragma unroll
      for (int mi = 0; mi < 4; ++mi) {
        int e = mi * 16 + lane16;
        int kb = ks * 64 + lgrp * 16;
        a[mi] = *(const short8*)((const char*)Xs + e * 512 + (kb ^ ((e & 7) << 4)));
      }
      short8 b[2];
      #pragma unroll
      for (int nf = 0; nf < 2; ++nf) {
        int n = ct * 128 + wave * 32 + nf * 16 + lane16;
        b[nf] = *(const short8*)(Wt + (size_t)n * 256 + ks * 32 + lgrp * 8);
      }
      #pragma unroll
      for (int mi = 0; mi < 4; ++mi)
        #pragma unroll
        for (int nf = 0; nf < 2; ++nf)
          acc[mi][nf] = __builtin_amdgcn_mfma_f32_16x16x32_bf16(a[mi], b[nf], acc[mi][nf], 0, 0, 0);
    }

    // epilogue: y[e][c] = sum_b (t[e][n]+pi_b[n]) * basis[e][b], 8-lane reduce
    const int b8 = lane & 7;
    #pragma unroll
    for (int nf = 0; nf < 2; ++nf) {
      int ncol = ct * 128 + wave * 32 + nf * 16 + lane16;
      float pib = pi_b[ncol];
      int cc = ct * 16 + wave * 4 + nf * 2 + (lane16 >> 3);
      #pragma unroll
      for (int mi = 0; mi < 4; ++mi) {
        #pragma unroll
        for (int i = 0; i < 4; ++i) {
          int e = mi * 16 + lgrp * 4 + i;
          float part = (acc[mi][nf][i] + pib) * basis_s[e * 8 + b8];
          part += __shfl_xor(part, 1);
          part += __shfl_xor(part, 2);
          part += __shfl_xor(part, 4);
          if (b8 == 0)
            *(ushort*)((char*)Ys + e * 256 + ((cc * 2) ^ ((e & 7) << 4))) = f2bf(part);
        }
      }
    }
  }
  __syncthreads();

  // --- ii GEMM: i1 = tanh(Y @ ii_w + ii_b) ---
  f32x4 acc2[4][2];
  #pragma unroll
  for (int mi = 0; mi < 4; ++mi)
    #pragma unroll
    for (int nf = 0; nf < 2; ++nf)
      acc2[mi][nf] = (f32x4){0.f, 0.f, 0.f, 0.f};

  #pragma unroll
  for (int ks = 0; ks < 4; ++ks) {
    short8 a[4];
    #pragma unroll
    for (int mi = 0; mi < 4; ++mi) {
      int e = mi * 16 + lane16;
      int kb = ks * 64 + lgrp * 16;
      a[mi] = *(const short8*)((const char*)Ys + e * 256 + (kb ^ ((e & 7) << 4)));
    }
    short8 b[2];
    #pragma unroll
    for (int nf = 0; nf < 2; ++nf) {
      int n = wave * 32 + nf * 16 + lane16;
      b[nf] = *(const short8*)(iiWt + n * 128 + ks * 32 + lgrp * 8);
    }
    #pragma unroll
    for (int mi = 0; mi < 4; ++mi)
      #pragma unroll
      for (int nf = 0; nf < 2; ++nf)
        acc2[mi][nf] = __builtin_amdgcn_mfma_f32_16x16x32_bf16(a[mi], b[nf], acc2[mi][nf], 0, 0, 0);
  }

  // --- scatter ---
  #pragma unroll
  for (int nf = 0; nf < 2; ++nf) {
    int cc = wave * 32 + nf * 16 + lane16;
    float bib = ii_b[cc];
    #pragma unroll
    for (int mi = 0; mi < 4; ++mi) {
      #pragma unroll
      for (int i = 0; i < 4; ++i) {
        int e = mi * 16 + lgrp * 4 + i;
        size_t eg = e0 + e;
        if (eg < (size_t)E) {
          float v = tanhf(acc2[mi][nf][i] + bib);
          unsafeAtomicAdd(out + (size_t)idxj_s[e] * 128 + cc, v);
        }
      }
    }
  }
}

extern "C" void kernel_launch(void* const* d_in, const int* in_sizes, int n_in,
                              void* d_out, int out_size, void* d_ws, size_t ws_size,
                              hipStream_t stream)
{
  const float* p1    = (const float*)d_in[0];
  const int*   idx_i = (const int*)d_in[1];
  const int*   idx_j = (const int*)d_in[2];
  const float* basis = (const float*)d_in[3];
  const float* pp_w1 = (const float*)d_in[4];
  const float* pp_b1 = (const float*)d_in[5];
  const float* pp_w2 = (const float*)d_in[6];
  const float* pp_b2 = (const float*)d_in[7];
  const float* pi_w  = (const float*)d_in[8];
  const float* pi_b  = (const float*)d_in[9];
  const float* ii_w  = (const float*)d_in[10];
  const float* ii_b  = (const float*)d_in[11];

  const int N = in_sizes[0] / 128;
  const int E = in_sizes[1];

  ushort* hbf  = (ushort*)d_ws;
  ushort* Wt   = (ushort*)((char*)d_ws + (size_t)N * 128 * 2);
  ushort* iiWt = (ushort*)((char*)Wt + (size_t)256 * 1024 * 2);

  hipMemsetAsync(d_out, 0, (size_t)out_size * sizeof(float), stream);

  prep_weights<<<dim3((256 * 1024 + 128 * 128 + 255) / 256), dim3(256), 0, stream>>>(
      pi_w, ii_w, Wt, iiWt);
  pp_kernel<<<dim3((N + 31) / 32), dim3(256), 0, stream>>>(
      p1, pp_w1, pp_b1, pp_w2, pp_b2, hbf, N);
  edge_kernel<<<dim3((E + 63) / 64), dim3(256), 0, stream>>>(
      hbf, idx_i, idx_j, basis, Wt, pi_b, iiWt, ii_b, (float*)d_out, E);
}

// Round 2
// 829.284 us; speedup vs baseline: 1.1659x; 1.1659x over previous
//
#include <hip/hip_runtime.h>

typedef __attribute__((ext_vector_type(8))) short short8;
typedef __attribute__((ext_vector_type(4))) float f32x4;

__device__ inline ushort f2bf(float f) {
  union { float f; unsigned u; } v; v.f = f;
  return (ushort)((v.u + 0x7fffu + ((v.u >> 16) & 1u)) >> 16);
}

// ---------------- weight prep: pack into per-MFMA-fragment order ----------------
// Wtp frag layout: [nt 0..63][ks 0..7][lane 0..63][m 0..7]
//   element: n = nt*16 + (lane&15), k = ks*32 + (lane>>4)*8 + m, value = bf16(pi_w[k*1024+n])
// iiWtp frag layout: [dt 0..7][ks 0..3][lane][m]
//   element: d = dt*16 + (lane&15), c = ks*32 + (lane>>4)*8 + m, value = bf16(ii_w[c*128+d])
__global__ __launch_bounds__(256)
void prep_weights(const float* __restrict__ pi_w, const float* __restrict__ ii_w,
                  ushort* __restrict__ Wtp, ushort* __restrict__ iiWtp)
{
  int tid = blockIdx.x * 256 + threadIdx.x;
  if (tid < 64 * 8 * 64 * 8) {
    int m = tid & 7, lane = (tid >> 3) & 63, ks = (tid >> 9) & 7, nt = tid >> 12;
    int k = ks * 32 + (lane >> 4) * 8 + m;
    int n = nt * 16 + (lane & 15);
    Wtp[tid] = f2bf(pi_w[k * 1024 + n]);
  } else {
    int t = tid - 262144;
    if (t < 8 * 4 * 64 * 8) {
      int m = t & 7, lane = (t >> 3) & 63, ks = (t >> 9) & 3, dt = t >> 11;
      int c = ks * 32 + (lane >> 4) * 8 + m;
      int d = dt * 16 + (lane & 15);
      iiWtp[t] = f2bf(ii_w[c * 128 + d]);
    }
  }
}

// ---------------- pp: h = tanh(tanh(p1@W1+b1)@W2+b2) -> bf16 ----------------
__global__ __launch_bounds__(256)
void pp_kernel(const float* __restrict__ p1,
               const float* __restrict__ w1, const float* __restrict__ b1,
               const float* __restrict__ w2, const float* __restrict__ b2,
               ushort* __restrict__ hbf, int N)
{
  __shared__ float p1s[32 * 128];
  __shared__ float h1s[32 * 128];
  const int tid = threadIdx.x;
  const int n0 = blockIdx.x * 32;

  #pragma unroll
  for (int p = 0; p < 4; ++p) {
    int off = (p * 256 + tid) * 4;
    int n = n0 + (off >> 7);
    float4 v = make_float4(0.f, 0.f, 0.f, 0.f);
    if (n < N) v = *(const float4*)(p1 + (size_t)n0 * 128 + off);
    *(float4*)(p1s + off) = v;
  }
  __syncthreads();

  const int c = tid & 127;
  const int nset = tid >> 7;
  float acc[16];

  #pragma unroll
  for (int n = 0; n < 16; ++n) acc[n] = b1[c];
  for (int k = 0; k < 128; k += 4) {
    float wa = w1[(k + 0) * 128 + c];
    float wb = w1[(k + 1) * 128 + c];
    float wc = w1[(k + 2) * 128 + c];
    float wd = w1[(k + 3) * 128 + c];
    #pragma unroll
    for (int n = 0; n < 16; ++n) {
      const float4 pv = *(const float4*)(p1s + (nset * 16 + n) * 128 + k);
      acc[n] += pv.x * wa + pv.y * wb + pv.z * wc + pv.w * wd;
    }
  }
  #pragma unroll
  for (int n = 0; n < 16; ++n) h1s[(nset * 16 + n) * 128 + c] = tanhf(acc[n]);
  __syncthreads();

  #pragma unroll
  for (int n = 0; n < 16; ++n) acc[n] = b2[c];
  for (int k = 0; k < 128; k += 4) {
    float wa = w2[(k + 0) * 128 + c];
    float wb = w2[(k + 1) * 128 + c];
    float wc = w2[(k + 2) * 128 + c];
    float wd = w2[(k + 3) * 128 + c];
    #pragma unroll
    for (int n = 0; n < 16; ++n) {
      const float4 pv = *(const float4*)(h1s + (nset * 16 + n) * 128 + k);
      acc[n] += pv.x * wa + pv.y * wb + pv.z * wc + pv.w * wd;
    }
  }
  #pragma unroll
  for (int n = 0; n < 16; ++n) {
    int node = n0 + nset * 16 + n;
    if (node < N) hbf[(size_t)node * 128 + c] = f2bf(tanhf(acc[n]));
  }
}

// ---------------- fused edge kernel (swapped-operand MFMA) ----------------
// Per block: 64 edges, 4 waves. Wave w owns n-range [w*256, w*256+256) of pi output.
// D[n][e] = mfma(A=Wtp frag (lane16->n), B=X frag (lane16->e)).
// Lane holds 4 consecutive n = 4 basis slots of one channel c -> basis fold is
// 4 register FMAs + one shfl_xor(16). Requires E % 64 == 0 (400000/64 = 6250).
__global__ __launch_bounds__(256, 2)
void edge_kernel(const ushort* __restrict__ hbf,
                 const int* __restrict__ idx_i, const int* __restrict__ idx_j,
                 const float* __restrict__ basis,
                 const ushort* __restrict__ Wtp,   // packed [64][8][64][8]
                 const float* __restrict__ pi_b,   // [1024]
                 const ushort* __restrict__ iiWtp, // packed [8][4][64][8]
                 const float* __restrict__ ii_b,   // [128]
                 float* __restrict__ out, int E)
{
  __shared__ ushort Xs[64 * 256];               // rows of 512B, byte ^= (e&7)<<4
  __shared__ ushort Ys[64 * 128];               // rows of 256B, byte ^= (e&7)<<4
  __shared__ alignas(16) float basis_s[64 * 8];
  __shared__ int idxj_s[64];

  const int tid = threadIdx.x;
  const int wave = tid >> 6;
  const int lane = tid & 63;
  const int lane16 = lane & 15;
  const int lgrp = lane >> 4;
  const size_t e0 = (size_t)blockIdx.x * 64;

  // --- stage X (gather 128 rows of 256B, coalesced 16B/lane) ---
  #pragma unroll
  for (int pass = 0; pass < 8; ++pass) {
    int r = pass * 16 + (tid >> 4);
    int l16 = tid & 15;
    int e = r >> 1;
    size_t eg = e0 + e;
    int node = (r & 1) ? idx_j[eg] : idx_i[eg];
    int4 v = *(const int4*)(hbf + (size_t)node * 128 + l16 * 8);
    int kb = ((r & 1) * 128 + l16 * 8) * 2;
    *(int4*)((char*)Xs + e * 512 + (kb ^ ((e & 7) << 4))) = v;
  }
  basis_s[tid] = basis[e0 * 8 + tid];
  basis_s[tid + 256] = basis[e0 * 8 + 256 + tid];
  if (tid < 64) idxj_s[tid] = idx_j[e0 + tid];
  __syncthreads();

  // --- hoist X fragments (ct-invariant) and basis fragments to registers ---
  short8 xf[4][8];
  #pragma unroll
  for (int et = 0; et < 4; ++et) {
    int e = et * 16 + lane16;
    #pragma unroll
    for (int ks = 0; ks < 8; ++ks)
      xf[et][ks] = *(const short8*)((const char*)Xs + e * 512 + ((ks * 64 + lgrp * 16) ^ ((e & 7) << 4)));
  }
  float4 bas[4];
  #pragma unroll
  for (int et = 0; et < 4; ++et) {
    int e = et * 16 + lane16;
    bas[et] = *(const float4*)((const char*)basis_s + e * 32 + (lgrp & 1) * 16);
  }

  // --- pi GEMM + basis fold: wave covers n-tiles [wave*16, wave*16+16) ---
  #pragma unroll 2
  for (int ct = 0; ct < 16; ++ct) {
    const int ntg = wave * 16 + ct;  // global n-tile (16 n's = 2 channels)
    const float4 pib = *(const float4*)(pi_b + ntg * 16 + lgrp * 4);
    f32x4 acc[4] = {{0.f,0.f,0.f,0.f},{0.f,0.f,0.f,0.f},{0.f,0.f,0.f,0.f},{0.f,0.f,0.f,0.f}};
    #pragma unroll
    for (int ks = 0; ks < 8; ++ks) {
      short8 a = *(const short8*)(Wtp + ((size_t)(ntg * 8 + ks) * 64 + lane) * 8);
      #pragma unroll
      for (int et = 0; et < 4; ++et)
        acc[et] = __builtin_amdgcn_mfma_f32_16x16x32_bf16(a, xf[et][ks], acc[et], 0, 0, 0);
    }
    // lane holds n = ntg*16 + lgrp*4 + i for edge e=lane16; b(i) = (lgrp&1)*4+i,
    // channel c = ntg*2 + (lgrp>>1). Fold basis in-register, pair-sum via 1 shuffle.
    const int cg = ntg * 2 + (lgrp >> 1);
    #pragma unroll
    for (int et = 0; et < 4; ++et) {
      int e = et * 16 + lane16;
      float part = (acc[et][0] + pib.x) * bas[et].x + (acc[et][1] + pib.y) * bas[et].y
                 + (acc[et][2] + pib.z) * bas[et].z + (acc[et][3] + pib.w) * bas[et].w;
      part += __shfl_xor(part, 16);
      if (!(lgrp & 1))
        *(ushort*)((char*)Ys + e * 256 + ((cg * 2) ^ ((e & 7) << 4))) = f2bf(part);
    }
  }
  __syncthreads();

  // --- ii GEMM (swapped): D[d][e], wave owns d-tiles {wave*2, wave*2+1} ---
  short8 yf[4][4];
  #pragma unroll
  for (int et = 0; et < 4; ++et) {
    int e = et * 16 + lane16;
    #pragma unroll
    for (int ks = 0; ks < 4; ++ks)
      yf[et][ks] = *(const short8*)((const char*)Ys + e * 256 + ((ks * 64 + lgrp * 16) ^ ((e & 7) << 4)));
  }

  f32x4 acc2[4][2];
  #pragma unroll
  for (int et = 0; et < 4; ++et)
    #pragma unroll
    for (int dtl = 0; dtl < 2; ++dtl)
      acc2[et][dtl] = (f32x4){0.f, 0.f, 0.f, 0.f};

  #pragma unroll
  for (int dtl = 0; dtl < 2; ++dtl) {
    const int dtg = wave * 2 + dtl;
    #pragma unroll
    for (int ks = 0; ks < 4; ++ks) {
      short8 a = *(const short8*)(iiWtp + ((size_t)(dtg * 4 + ks) * 64 + lane) * 8);
      #pragma unroll
      for (int et = 0; et < 4; ++et)
        acc2[et][dtl] = __builtin_amdgcn_mfma_f32_16x16x32_bf16(a, yf[et][ks], acc2[et][dtl], 0, 0, 0);
    }
  }

  float4 iib[2];
  #pragma unroll
  for (int dtl = 0; dtl < 2; ++dtl)
    iib[dtl] = *(const float4*)(ii_b + (wave * 2 + dtl) * 16 + lgrp * 4);

  // --- tanh + scatter-add: lane owns 4 consecutive d for edge e=lane16 ---
  #pragma unroll
  for (int et = 0; et < 4; ++et) {
    int e = et * 16 + lane16;
    float* op = out + (size_t)idxj_s[e] * 128;
    #pragma unroll
    for (int dtl = 0; dtl < 2; ++dtl) {
      int d0 = (wave * 2 + dtl) * 16 + lgrp * 4;
      #pragma unroll
      for (int i = 0; i < 4; ++i) {
        float v = tanhf(acc2[et][dtl][i] + iib[dtl][i]);
        unsafeAtomicAdd(op + d0 + i, v);
      }
    }
  }
}

extern "C" void kernel_launch(void* const* d_in, const int* in_sizes, int n_in,
                              void* d_out, int out_size, void* d_ws, size_t ws_size,
                              hipStream_t stream)
{
  const float* p1    = (const float*)d_in[0];
  const int*   idx_i = (const int*)d_in[1];
  const int*   idx_j = (const int*)d_in[2];
  const float* basis = (const float*)d_in[3];
  const float* pp_w1 = (const float*)d_in[4];
  const float* pp_b1 = (const float*)d_in[5];
  const float* pp_w2 = (const float*)d_in[6];
  const float* pp_b2 = (const float*)d_in[7];
  const float* pi_w  = (const float*)d_in[8];
  const float* pi_b  = (const float*)d_in[9];
  const float* ii_w  = (const float*)d_in[10];
  const float* ii_b  = (const float*)d_in[11];

  const int N = in_sizes[0] / 128;
  const int E = in_sizes[1];

  ushort* hbf   = (ushort*)d_ws;
  ushort* Wtp   = (ushort*)((char*)d_ws + (size_t)N * 128 * 2);
  ushort* iiWtp = (ushort*)((char*)Wtp + (size_t)262144 * 2);

  hipMemsetAsync(d_out, 0, (size_t)out_size * sizeof(float), stream);

  prep_weights<<<dim3((262144 + 16384) / 256), dim3(256), 0, stream>>>(
      pi_w, ii_w, Wtp, iiWtp);
  pp_kernel<<<dim3((N + 31) / 32), dim3(256), 0, stream>>>(
      p1, pp_w1, pp_b1, pp_w2, pp_b2, hbf, N);
  edge_kernel<<<dim3(E / 64), dim3(256), 0, stream>>>(
      hbf, idx_i, idx_j, basis, Wtp, pi_b, iiWtp, ii_b, (float*)d_out, E);
}

// Round 3
// 496.298 us; speedup vs baseline: 1.9482x; 1.6709x over previous
//
#include <hip/hip_runtime.h>

typedef __attribute__((ext_vector_type(8))) short short8;
typedef __attribute__((ext_vector_type(4))) float f32x4;

__device__ inline ushort f2bf(float f) {
  union { float f; unsigned u; } v; v.f = f;
  return (ushort)((v.u + 0x7fffu + ((v.u >> 16) & 1u)) >> 16);
}

// ---------------- weight prep: pack into per-MFMA-fragment order ----------------
__global__ __launch_bounds__(256)
void prep_weights(const float* __restrict__ pi_w, const float* __restrict__ ii_w,
                  ushort* __restrict__ Wtp, ushort* __restrict__ iiWtp)
{
  int tid = blockIdx.x * 256 + threadIdx.x;
  if (tid < 64 * 8 * 64 * 8) {
    int m = tid & 7, lane = (tid >> 3) & 63, ks = (tid >> 9) & 7, nt = tid >> 12;
    int k = ks * 32 + (lane >> 4) * 8 + m;
    int n = nt * 16 + (lane & 15);
    Wtp[tid] = f2bf(pi_w[k * 1024 + n]);
  } else {
    int t = tid - 262144;
    if (t < 8 * 4 * 64 * 8) {
      int m = t & 7, lane = (t >> 3) & 63, ks = (t >> 9) & 3, dt = t >> 11;
      int c = ks * 32 + (lane >> 4) * 8 + m;
      int d = dt * 16 + (lane & 15);
      iiWtp[t] = f2bf(ii_w[c * 128 + d]);
    }
  }
}

// ---------------- pp: h = tanh(tanh(p1@W1+b1)@W2+b2) -> bf16 ----------------
__global__ __launch_bounds__(256)
void pp_kernel(const float* __restrict__ p1,
               const float* __restrict__ w1, const float* __restrict__ b1,
               const float* __restrict__ w2, const float* __restrict__ b2,
               ushort* __restrict__ hbf, int N)
{
  __shared__ float p1s[32 * 128];
  __shared__ float h1s[32 * 128];
  const int tid = threadIdx.x;
  const int n0 = blockIdx.x * 32;

  #pragma unroll
  for (int p = 0; p < 4; ++p) {
    int off = (p * 256 + tid) * 4;
    int n = n0 + (off >> 7);
    float4 v = make_float4(0.f, 0.f, 0.f, 0.f);
    if (n < N) v = *(const float4*)(p1 + (size_t)n0 * 128 + off);
    *(float4*)(p1s + off) = v;
  }
  __syncthreads();

  const int c = tid & 127;
  const int nset = tid >> 7;
  float acc[16];

  #pragma unroll
  for (int n = 0; n < 16; ++n) acc[n] = b1[c];
  for (int k = 0; k < 128; k += 4) {
    float wa = w1[(k + 0) * 128 + c];
    float wb = w1[(k + 1) * 128 + c];
    float wc = w1[(k + 2) * 128 + c];
    float wd = w1[(k + 3) * 128 + c];
    #pragma unroll
    for (int n = 0; n < 16; ++n) {
      const float4 pv = *(const float4*)(p1s + (nset * 16 + n) * 128 + k);
      acc[n] += pv.x * wa + pv.y * wb + pv.z * wc + pv.w * wd;
    }
  }
  #pragma unroll
  for (int n = 0; n < 16; ++n) h1s[(nset * 16 + n) * 128 + c] = tanhf(acc[n]);
  __syncthreads();

  #pragma unroll
  for (int n = 0; n < 16; ++n) acc[n] = b2[c];
  for (int k = 0; k < 128; k += 4) {
    float wa = w2[(k + 0) * 128 + c];
    float wb = w2[(k + 1) * 128 + c];
    float wc = w2[(k + 2) * 128 + c];
    float wd = w2[(k + 3) * 128 + c];
    #pragma unroll
    for (int n = 0; n < 16; ++n) {
      const float4 pv = *(const float4*)(h1s + (nset * 16 + n) * 128 + k);
      acc[n] += pv.x * wa + pv.y * wb + pv.z * wc + pv.w * wd;
    }
  }
  #pragma unroll
  for (int n = 0; n < 16; ++n) {
    int node = n0 + nset * 16 + n;
    if (node < N) hbf[(size_t)node * 128 + c] = f2bf(tanhf(acc[n]));
  }
}

// ---------------- fused edge kernel (swapped-operand MFMA) ----------------
__global__ __launch_bounds__(256, 2)
void edge_kernel(const ushort* __restrict__ hbf,
                 const int* __restrict__ idx_i, const int* __restrict__ idx_j,
                 const float* __restrict__ basis,
                 const ushort* __restrict__ Wtp,   // packed [64][8][64][8]
                 const float* __restrict__ pi_b,   // [1024]
                 const ushort* __restrict__ iiWtp, // packed [8][4][64][8]
                 const float* __restrict__ ii_b,   // [128]
                 float* __restrict__ out, int E)
{
  __shared__ ushort Xs[64 * 256];               // 32 KB; later reused as f32 transpose buf
  __shared__ ushort Ys[64 * 128];               // rows of 256B, byte ^= (e&7)<<4
  __shared__ alignas(16) float basis_s[64 * 8];
  __shared__ int idxj_s[64];

  const int tid = threadIdx.x;
  const int wave = tid >> 6;
  const int lane = tid & 63;
  const int lane16 = lane & 15;
  const int lgrp = lane >> 4;
  const size_t e0 = (size_t)blockIdx.x * 64;

  // --- stage X (gather 128 rows of 256B, coalesced 16B/lane) ---
  #pragma unroll
  for (int pass = 0; pass < 8; ++pass) {
    int r = pass * 16 + (tid >> 4);
    int l16 = tid & 15;
    int e = r >> 1;
    size_t eg = e0 + e;
    int node = (r & 1) ? idx_j[eg] : idx_i[eg];
    int4 v = *(const int4*)(hbf + (size_t)node * 128 + l16 * 8);
    int kb = ((r & 1) * 128 + l16 * 8) * 2;
    *(int4*)((char*)Xs + e * 512 + (kb ^ ((e & 7) << 4))) = v;
  }
  basis_s[tid] = basis[e0 * 8 + tid];
  basis_s[tid + 256] = basis[e0 * 8 + 256 + tid];
  if (tid < 64) idxj_s[tid] = idx_j[e0 + tid];
  __syncthreads();

  // --- hoist X fragments to registers and PIN them (128 VGPRs) ---
  short8 xf[4][8];
  #pragma unroll
  for (int et = 0; et < 4; ++et) {
    int e = et * 16 + lane16;
    #pragma unroll
    for (int ks = 0; ks < 8; ++ks) {
      xf[et][ks] = *(const short8*)((const char*)Xs + e * 512 + ((ks * 64 + lgrp * 16) ^ ((e & 7) << 4)));
      asm volatile("" : "+v"(xf[et][ks]));   // forbid remat-from-LDS
    }
  }
  float4 bas[4];
  #pragma unroll
  for (int et = 0; et < 4; ++et) {
    int e = et * 16 + lane16;
    bas[et] = *(const float4*)((const char*)basis_s + e * 32 + (lgrp & 1) * 16);
  }

  // --- pi GEMM + basis fold: wave covers n-tiles [wave*16, wave*16+16) ---
  #pragma unroll
  for (int ct = 0; ct < 16; ++ct) {
    const int ntg = wave * 16 + ct;
    const float4 pib = *(const float4*)(pi_b + ntg * 16 + lgrp * 4);
    f32x4 acc[4] = {{0.f,0.f,0.f,0.f},{0.f,0.f,0.f,0.f},{0.f,0.f,0.f,0.f},{0.f,0.f,0.f,0.f}};
    #pragma unroll
    for (int ks = 0; ks < 8; ++ks) {
      short8 a = *(const short8*)(Wtp + ((size_t)(ntg * 8 + ks) * 64 + lane) * 8);
      #pragma unroll
      for (int et = 0; et < 4; ++et)
        acc[et] = __builtin_amdgcn_mfma_f32_16x16x32_bf16(a, xf[et][ks], acc[et], 0, 0, 0);
    }
    const int cg = ntg * 2 + (lgrp >> 1);
    #pragma unroll
    for (int et = 0; et < 4; ++et) {
      int e = et * 16 + lane16;
      float part = (acc[et][0] + pib.x) * bas[et].x + (acc[et][1] + pib.y) * bas[et].y
                 + (acc[et][2] + pib.z) * bas[et].z + (acc[et][3] + pib.w) * bas[et].w;
      part += __shfl_xor(part, 16);
      if (!(lgrp & 1))
        *(ushort*)((char*)Ys + e * 256 + ((cg * 2) ^ ((e & 7) << 4))) = f2bf(part);
    }
  }
  __syncthreads();   // Ys ready; also: all waves finished reading Xs (xf loads precede pi loop)

  // --- ii GEMM (swapped): D[d][e], wave owns d-tiles {wave*2, wave*2+1} ---
  short8 yf[4][4];
  #pragma unroll
  for (int et = 0; et < 4; ++et) {
    int e = et * 16 + lane16;
    #pragma unroll
    for (int ks = 0; ks < 4; ++ks)
      yf[et][ks] = *(const short8*)((const char*)Ys + e * 256 + ((ks * 64 + lgrp * 16) ^ ((e & 7) << 4)));
  }

  f32x4 acc2[4][2];
  #pragma unroll
  for (int et = 0; et < 4; ++et)
    #pragma unroll
    for (int dtl = 0; dtl < 2; ++dtl)
      acc2[et][dtl] = (f32x4){0.f, 0.f, 0.f, 0.f};

  #pragma unroll
  for (int dtl = 0; dtl < 2; ++dtl) {
    const int dtg = wave * 2 + dtl;
    #pragma unroll
    for (int ks = 0; ks < 4; ++ks) {
      short8 a = *(const short8*)(iiWtp + ((size_t)(dtg * 4 + ks) * 64 + lane) * 8);
      #pragma unroll
      for (int et = 0; et < 4; ++et)
        acc2[et][dtl] = __builtin_amdgcn_mfma_f32_16x16x32_bf16(a, yf[et][ks], acc2[et][dtl], 0, 0, 0);
    }
  }

  float4 iib[2];
  #pragma unroll
  for (int dtl = 0; dtl < 2; ++dtl)
    iib[dtl] = *(const float4*)(ii_b + (wave * 2 + dtl) * 16 + lgrp * 4);

  // --- tanh, transpose through LDS (reuse Xs as f32 [64][128], swizzled) ---
  float* Tr = (float*)Xs;
  #pragma unroll
  for (int dtl = 0; dtl < 2; ++dtl) {
    int d0 = (wave * 2 + dtl) * 16 + lgrp * 4;
    #pragma unroll
    for (int et = 0; et < 4; ++et) {
      int e = et * 16 + lane16;
      float4 v;
      v.x = tanhf(acc2[et][dtl][0] + iib[dtl].x);
      v.y = tanhf(acc2[et][dtl][1] + iib[dtl].y);
      v.z = tanhf(acc2[et][dtl][2] + iib[dtl].z);
      v.w = tanhf(acc2[et][dtl][3] + iib[dtl].w);
      *(float4*)((char*)Tr + e * 512 + ((d0 * 4) ^ ((e & 7) << 4))) = v;
    }
  }
  __syncthreads();

  // --- coalesced scatter: each wave-instruction = 64 consecutive addresses ---
  #pragma unroll
  for (int p = 0; p < 32; ++p) {
    int flat = p * 256 + tid;          // 0..8191
    int e = flat >> 7;
    int c = flat & 127;
    float v = *(const float*)((const char*)Tr + e * 512 + ((c * 4) ^ ((e & 7) << 4)));
    unsafeAtomicAdd(out + (size_t)idxj_s[e] * 128 + c, v);
  }
}

extern "C" void kernel_launch(void* const* d_in, const int* in_sizes, int n_in,
                              void* d_out, int out_size, void* d_ws, size_t ws_size,
                              hipStream_t stream)
{
  const float* p1    = (const float*)d_in[0];
  const int*   idx_i = (const int*)d_in[1];
  const int*   idx_j = (const int*)d_in[2];
  const float* basis = (const float*)d_in[3];
  const float* pp_w1 = (const float*)d_in[4];
  const float* pp_b1 = (const float*)d_in[5];
  const float* pp_w2 = (const float*)d_in[6];
  const float* pp_b2 = (const float*)d_in[7];
  const float* pi_w  = (const float*)d_in[8];
  const float* pi_b  = (const float*)d_in[9];
  const float* ii_w  = (const float*)d_in[10];
  const float* ii_b  = (const float*)d_in[11];

  const int N = in_sizes[0] / 128;
  const int E = in_sizes[1];

  ushort* hbf   = (ushort*)d_ws;
  ushort* Wtp   = (ushort*)((char*)d_ws + (size_t)N * 128 * 2);
  ushort* iiWtp = (ushort*)((char*)Wtp + (size_t)262144 * 2);

  hipMemsetAsync(d_out, 0, (size_t)out_size * sizeof(float), stream);

  prep_weights<<<dim3((262144 + 16384) / 256), dim3(256), 0, stream>>>(
      pi_w, ii_w, Wtp, iiWtp);
  pp_kernel<<<dim3((N + 31) / 32), dim3(256), 0, stream>>>(
      p1, pp_w1, pp_b1, pp_w2, pp_b2, hbf, N);
  edge_kernel<<<dim3(E / 64), dim3(256), 0, stream>>>(
      hbf, idx_i, idx_j, basis, Wtp, pi_b, iiWtp, ii_b, (float*)d_out, E);
}